// Round 13
// baseline (133.425 us; speedup 1.0000x reference)
//
#include <hip/hip_runtime.h>
#include <hip/hip_bf16.h>
#include <math.h>

#define B 4
#define N 2048
#define FIN 256
#define H 4
#define FO 64
#define M (B*N)        // 8192 rows
#define HF (H*FO)      // 256 cols

typedef __attribute__((ext_vector_type(8))) short short8;   // 8 bf16 (4 VGPRs)
typedef __attribute__((ext_vector_type(4))) float float4v;  // MFMA C/D
typedef __attribute__((ext_vector_type(4))) int int4v;

#if __has_builtin(__builtin_amdgcn_exp2f)
#define EXP2(x) __builtin_amdgcn_exp2f(x)
#else
#define EXP2(x) exp2f(x)
#endif

// pack two f32 -> two bf16 (RNE) in one dword
static __device__ __forceinline__ unsigned int pk_rne(float a, float b) {
  unsigned int ua = __builtin_bit_cast(unsigned int, a);
  unsigned int ub = __builtin_bit_cast(unsigned int, b);
  ua += 0x7fffu + ((ua >> 16) & 1u);
  ub += 0x7fffu + ((ub >> 16) & 1u);
  return (ua >> 16) | (ub & 0xffff0000u);
}

// pack two f32 -> two bf16 (truncate) in one dword: 1 v_perm_b32
static __device__ __forceinline__ unsigned int pk_trunc(float a, float b) {
#if __has_builtin(__builtin_amdgcn_perm)
  return __builtin_amdgcn_perm(__builtin_bit_cast(unsigned int, b),
                               __builtin_bit_cast(unsigned int, a), 0x07060302u);
#else
  return (__builtin_bit_cast(unsigned int, a) >> 16) |
         (__builtin_bit_cast(unsigned int, b) & 0xffff0000u);
#endif
}

// split x into hi (truncated bf16) + lo (truncated bf16 of remainder), packed pairs
static __device__ __forceinline__ void split_pair(float x0, float x1,
                                                  unsigned int& hi, unsigned int& lo) {
  unsigned int u0 = __builtin_bit_cast(unsigned int, x0);
  unsigned int u1 = __builtin_bit_cast(unsigned int, x1);
  hi = (u0 >> 16) | (u1 & 0xffff0000u);
  float h0 = __builtin_bit_cast(float, u0 & 0xffff0000u);
  float h1 = __builtin_bit_cast(float, u1 & 0xffff0000u);
  unsigned int l0 = __builtin_bit_cast(unsigned int, x0 - h0);
  unsigned int l1 = __builtin_bit_cast(unsigned int, x1 - h1);
  lo = (l0 >> 16) | (l1 & 0xffff0000u);
}

// monotone float<->uint encoding for atomicMax
static __device__ __forceinline__ unsigned int fenc(float f) {
  unsigned int b = __builtin_bit_cast(unsigned int, f);
  return (b & 0x80000000u) ? ~b : (b | 0x80000000u);
}
static __device__ __forceinline__ float fdec(unsigned int e) {
  unsigned int b = (e & 0x80000000u) ? (e & 0x7fffffffu) : ~e;
  return __builtin_bit_cast(float, b);
}

// ---- Kernel 1: [0..15] W -> Wf (fragment-ordered bf16 hi/lo pair)
//      [16..143] X -> Xf (fragment-ordered A-operand bf16 hi/lo pair)
//      [144..2191] adj rows -> bitmasks
__global__ __launch_bounds__(256) void prep_pack(const float* __restrict__ Wsrc,
                                                 const float* __restrict__ X,
                                                 const float* __restrict__ adj,
                                                 unsigned short* __restrict__ Wf_hi,
                                                 unsigned short* __restrict__ Wf_lo,
                                                 unsigned short* __restrict__ Xf_hi,
                                                 unsigned short* __restrict__ Xf_lo,
                                                 unsigned long long* __restrict__ packed,
                                                 unsigned int* __restrict__ DmaxEnc) {
  const int blk = blockIdx.x;
  const int t = threadIdx.x;
  if (blk >= 144) {
    const int row = blk - 144;
    const int w = t >> 6, l = t & 63;
    const float* ar = adj + (size_t)row * N;
    for (int c = w; c < N / 64; c += 4) {
      unsigned long long m = __ballot(ar[c * 64 + l] != 0.f);
      if (l == 0) packed[(size_t)row * (N / 64) + c] = m;
    }
    return;
  }
  __shared__ float lds[64][65];
  if (blk < 16) {
    if (blk == 0 && t < 16) DmaxEnc[t] = 0u;
    const int k0 = (blk >> 2) * 64;
    const int h  = blk & 3;
    const int n0 = h * 64;
    const int c4 = (t & 15) * 4;
    #pragma unroll
    for (int rep = 0; rep < 4; ++rep) {
      const int kl = (t >> 4) + 16 * rep;
      const float4 v = *(const float4*)(Wsrc + (size_t)(k0 + kl) * HF + n0 + c4);
      lds[kl][c4 + 0] = v.x; lds[kl][c4 + 1] = v.y;
      lds[kl][c4 + 2] = v.z; lds[kl][c4 + 3] = v.w;
    }
    __syncthreads();
    #pragma unroll
    for (int rep = 0; rep < 2; ++rep) {
      const int s   = t + rep * 256;
      const int kcl = s >> 8;
      const int tt  = (s >> 6) & 3;
      const int ln  = s & 63;
      const int fL  = tt * 16 + (ln & 15);
      const int kb  = kcl * 32 + (ln >> 4) * 8;
      unsigned int hv[4], lv[4];
      #pragma unroll
      for (int p = 0; p < 4; ++p)
        split_pair(lds[kb + 2 * p][fL], lds[kb + 2 * p + 1][fL], hv[p], lv[p]);
      const size_t off = ((((size_t)h * 8 + (k0 >> 5) + kcl) * 4 + tt) << 9) + ln * 8;
      *(uint4*)(Wf_hi + off) = make_uint4(hv[0], hv[1], hv[2], hv[3]);
      *(uint4*)(Wf_lo + off) = make_uint4(lv[0], lv[1], lv[2], lv[3]);
    }
    return;
  }
  // ---- X prep: xblk in [0,128), rows xblk*64..+64, A-fragment order ----
  const int xblk  = blk - 16;
  const int mrow0 = xblk * 64;
  for (int ktile = 0; ktile < 4; ++ktile) {
    if (ktile) __syncthreads();
    const int k0 = ktile * 64;
    const int c4 = (t & 15) * 4;
    #pragma unroll
    for (int rep = 0; rep < 4; ++rep) {
      const int rl = (t >> 4) + 16 * rep;
      const float4 v = *(const float4*)(X + (size_t)(mrow0 + rl) * FIN + k0 + c4);
      lds[rl][c4 + 0] = v.x; lds[rl][c4 + 1] = v.y;
      lds[rl][c4 + 2] = v.z; lds[rl][c4 + 3] = v.w;
    }
    __syncthreads();
    #pragma unroll
    for (int rep = 0; rep < 2; ++rep) {
      const int s   = t + rep * 256;
      const int mt  = s >> 7;
      const int kcl = (s >> 6) & 1;
      const int ln  = s & 63;
      const int mrl = mt * 16 + (ln & 15);
      const int kb  = kcl * 32 + (ln >> 4) * 8;
      unsigned int hv[4], lv[4];
      #pragma unroll
      for (int p = 0; p < 4; ++p)
        split_pair(lds[mrl][kb + 2 * p], lds[mrl][kb + 2 * p + 1], hv[p], lv[p]);
      const size_t off = (((size_t)(xblk * 4 + mt) * 8 + (ktile * 2 + kcl)) << 9) + ln * 8;
      *(uint4*)(Xf_hi + off) = make_uint4(hv[0], hv[1], hv[2], hv[3]);
      *(uint4*)(Xf_lo + off) = make_uint4(lv[0], lv[1], lv[2], lv[3]);
    }
  }
}

// ---- Kernel 2: fused h=x@W (bf16x2 MFMA) with register double-buffer ----
// Grid: (M/64)*H = 512 blocks, 256 thr (4 waves). XCD-swizzled.
__global__ __launch_bounds__(256) void gemm_fused(const unsigned short* __restrict__ Xf_hi,
                                                  const unsigned short* __restrict__ Xf_lo,
                                                  const unsigned short* __restrict__ Wf_hi,
                                                  const unsigned short* __restrict__ Wf_lo,
                                                  const float* __restrict__ a_src,
                                                  const float* __restrict__ a_dst,
                                                  float* __restrict__ Srcv,
                                                  float2* __restrict__ Epair,
                                                  unsigned int* __restrict__ DmaxEnc,
                                                  unsigned short* __restrict__ Hf) {
  __shared__ unsigned short sh[64][72];
  __shared__ float smax[4];
  const int xcd  = blockIdx.x & 7;
  const int slot = blockIdx.x >> 3;
  const int mb = xcd * 16 + (slot >> 2);
  const int h  = slot & 3;
  const int w = threadIdx.x >> 6, lane = threadIdx.x & 63;
  const int fl = lane & 15, quad = lane >> 4;
  const float L2E = 1.4426950408889634f;

  const float4v zero = {0.f, 0.f, 0.f, 0.f};
  float4v acc[4] = {zero, zero, zero, zero};

  const size_t abase = (((size_t)(mb * 4 + w) * 8) << 9) + lane * 8;
  const size_t wbase = (((size_t)h * 8) * 4 << 9) + lane * 8;

  // prefetch kc=0
  short8 nAhi = *(const short8*)(Xf_hi + abase);
  short8 nAlo = *(const short8*)(Xf_lo + abase);
  short8 nBhi[4], nBlo[4];
  #pragma unroll
  for (int t = 0; t < 4; ++t) {
    nBhi[t] = *(const short8*)(Wf_hi + wbase + ((size_t)t << 9));
    nBlo[t] = *(const short8*)(Wf_lo + wbase + ((size_t)t << 9));
  }
  #pragma unroll
  for (int kc = 0; kc < 8; ++kc) {
    const short8 Ahi = nAhi, Alo = nAlo;
    short8 Bhi[4], Blo[4];
    #pragma unroll
    for (int t = 0; t < 4; ++t) { Bhi[t] = nBhi[t]; Blo[t] = nBlo[t]; }
    if (kc < 7) {
      nAhi = *(const short8*)(Xf_hi + abase + ((size_t)(kc + 1) << 9));
      nAlo = *(const short8*)(Xf_lo + abase + ((size_t)(kc + 1) << 9));
      #pragma unroll
      for (int t = 0; t < 4; ++t) {
        const size_t woff = wbase + ((size_t)((kc + 1) * 4 + t) << 9);
        nBhi[t] = *(const short8*)(Wf_hi + woff);
        nBlo[t] = *(const short8*)(Wf_lo + woff);
      }
    }
    #pragma unroll
    for (int t = 0; t < 4; ++t) {
      acc[t] = __builtin_amdgcn_mfma_f32_16x16x32_bf16(Ahi, Bhi[t], acc[t], 0, 0, 0);
      acc[t] = __builtin_amdgcn_mfma_f32_16x16x32_bf16(Alo, Bhi[t], acc[t], 0, 0, 0);
      acc[t] = __builtin_amdgcn_mfma_f32_16x16x32_bf16(Ahi, Blo[t], acc[t], 0, 0, 0);
    }
  }

  // ---- Src dot, E-pair, wave max of d ----
  const int bb  = (mb * 64) >> 11;
  const int n0w = (mb * 64) & (N - 1);
  const int bh  = bb * H + h;
  float as[4], ad[4];
  #pragma unroll
  for (int t = 0; t < 4; ++t) {
    as[t] = a_src[h * FO + t * 16 + fl];
    ad[t] = a_dst[h * FO + t * 16 + fl];
  }
  float wmax = -INFINITY;
  #pragma unroll
  for (int reg = 0; reg < 4; ++reg) {
    float sv = 0.f, dv = 0.f;
    #pragma unroll
    for (int t = 0; t < 4; ++t) {
      sv = fmaf(acc[t][reg], as[t], sv);
      dv = fmaf(acc[t][reg], ad[t], dv);
    }
    #pragma unroll
    for (int off = 1; off <= 8; off <<= 1) {
      sv += __shfl_xor(sv, off, 64);
      dv += __shfl_xor(dv, off, 64);
    }
    wmax = fmaxf(wmax, dv);
    if (fl == 0) {
      const int node = n0w + w * 16 + quad * 4 + reg;
      Srcv[(bh << 11) + node] = sv;
      float2 e;
      e.x = EXP2(dv * L2E);            // exp(d)
      e.y = EXP2(dv * (0.2f * L2E));   // exp(0.2 d)
      Epair[(bh << 11) + node] = e;
    }
  }
  wmax = fmaxf(wmax, __shfl_xor(wmax, 16, 64));
  wmax = fmaxf(wmax, __shfl_xor(wmax, 32, 64));
  if (lane == 0) smax[w] = wmax;

  // ---- stage bf16 tile: sh[f][node] ----
  #pragma unroll
  for (int t = 0; t < 4; ++t) {
    const int nl = w * 16 + quad * 4;
    *(unsigned int*)&sh[t * 16 + fl][nl]     = pk_rne(acc[t][0], acc[t][1]);
    *(unsigned int*)&sh[t * 16 + fl][nl + 2] = pk_rne(acc[t][2], acc[t][3]);
  }
  __syncthreads();
  if (threadIdx.x == 0) {
    const float bmax = fmaxf(fmaxf(smax[0], smax[1]), fmaxf(smax[2], smax[3]));
    atomicMax(DmaxEnc + bh, fenc(bmax));
  }
  // ---- fragment-ordered Hf write ----
  const int jc0 = n0w >> 5;
  #pragma unroll
  for (int rep = 0; rep < 2; ++rep) {
    const int s = (int)threadIdx.x + rep * 256;
    const int jcl = s >> 8;
    const int tt  = (s >> 6) & 3;
    const int ln  = s & 63;
    const int f    = tt * 16 + (ln & 15);
    const int node = jcl * 32 + (ln >> 4) * 8;
    unsigned short* dsth = Hf + (((size_t)bh * 64 + jc0 + jcl) * 4 + tt) * 512 + ln * 8;
    *(uint4*)dsth = *(const uint4*)&sh[f][node];
  }
}

// ---- Kernel 3: MFMA flash aggregation (v11: 16 waves + reg dbuf + max-trick)
// Grid: B*(N/32)=256 blocks, 1024 thr (16 waves: 4 heads x 4 j-quarters),
// 2-row waves, 16 chunks each. p = mask * max(c1*E1, c2*E2) — exact since
// exp(leaky(u)) = max(e^u, e^0.2u) (exp monotone, leaky = max(u,.2u)).
// NOTE: plain __launch_bounds__ — min-waves bound splits the unified
// VGPR/AGPR file and spills (r9: 172MB scratch). Never force it.
__global__ __launch_bounds__(1024) void gat_mfma(const unsigned char* __restrict__ pb,
                                                 const float* __restrict__ Src,
                                                 const float2* __restrict__ Epair,
                                                 const unsigned int* __restrict__ DmaxEnc,
                                                 const unsigned short* __restrict__ Hf,
                                                 float* __restrict__ out) {
  const int xcd  = blockIdx.x & 7;
  const int slot = blockIdx.x >> 3;          // 0..31
  const int b    = xcd >> 1;
  const int i0   = ((xcd & 1) * 32 + slot) * 32;
  const int w    = threadIdx.x >> 6;         // 0..15
  const int lane = threadIdx.x & 63;
  const int h    = w & 3;
  const int q    = w >> 2;                   // j quarter
  const int bh   = b * H + h;
  const int fl   = lane & 15;
  const int kk   = (lane >> 4) * 8;
  const float L2E = 1.4426950408889634f;

  const int row0 = i0 + fl;
  const int row1 = i0 + 16 + fl;
  const float dmx = fdec(DmaxEnc[bh]);
  const float s0 = Src[(bh << 11) + row0];
  const float s1 = Src[(bh << 11) + row1];
  const float u0 = s0 + dmx, m0 = fmaxf(u0, 0.2f * u0);
  const float u1 = s1 + dmx, m1 = fmaxf(u1, 0.2f * u1);
  const float c1a = EXP2((s0 - m0) * L2E), c2a = EXP2((0.2f * s0 - m0) * L2E);
  const float c1b = EXP2((s1 - m1) * L2E), c2b = EXP2((0.2f * s1 - m1) * L2E);
  const float* ep = (const float*)(Epair + (bh << 11));
  const unsigned char* pb0 = pb + (size_t)row0 * (N / 8);
  const unsigned char* pb1 = pb + (size_t)row1 * (N / 8);
  const unsigned short* hfb = Hf + (size_t)bh * 64 * 2048 + lane * 8;

  const short onebf = 0x3F80;
  short8 ones;
  #pragma unroll
  for (int jj = 0; jj < 8; ++jj) ones[jj] = onebf;

  const float4v zero = {0.f, 0.f, 0.f, 0.f};
  float4v acc[2][4];
  float4v accL[2];
  #pragma unroll
  for (int rt = 0; rt < 2; ++rt) {
    accL[rt] = zero;
    #pragma unroll
    for (int t = 0; t < 4; ++t) acc[rt][t] = zero;
  }

  const int jbeg = q * (N / 4);
  // ---- prefetch chunk 0 ----
  short8 nb0, nb1, nb2, nb3;
  float4 nq0, nq1, nq2, nq3;
  unsigned int nm0, nm1;
  {
    const unsigned short* hc = hfb + (size_t)(jbeg >> 5) * 2048;
    nb0 = *(const short8*)(hc + 0 * 512);
    nb1 = *(const short8*)(hc + 1 * 512);
    nb2 = *(const short8*)(hc + 2 * 512);
    nb3 = *(const short8*)(hc + 3 * 512);
    nq0 = *(const float4*)(ep + 2 * (jbeg + kk) + 0);
    nq1 = *(const float4*)(ep + 2 * (jbeg + kk) + 4);
    nq2 = *(const float4*)(ep + 2 * (jbeg + kk) + 8);
    nq3 = *(const float4*)(ep + 2 * (jbeg + kk) + 12);
    nm0 = pb0[(jbeg + kk) >> 3];
    nm1 = pb1[(jbeg + kk) >> 3];
  }

  for (int it = 0; it < 16; ++it) {
    const short8 b0 = nb0, b1 = nb1, b2 = nb2, b3 = nb3;
    const float4 q0 = nq0, q1 = nq1, q2 = nq2, q3 = nq3;
    const unsigned int mk0 = nm0, mk1 = nm1;
    if (it < 15) {
      const int jn = jbeg + (it + 1) * 32;
      const unsigned short* hc = hfb + (size_t)(jn >> 5) * 2048;
      nb0 = *(const short8*)(hc + 0 * 512);
      nb1 = *(const short8*)(hc + 1 * 512);
      nb2 = *(const short8*)(hc + 2 * 512);
      nb3 = *(const short8*)(hc + 3 * 512);
      nq0 = *(const float4*)(ep + 2 * (jn + kk) + 0);
      nq1 = *(const float4*)(ep + 2 * (jn + kk) + 4);
      nq2 = *(const float4*)(ep + 2 * (jn + kk) + 8);
      nq3 = *(const float4*)(ep + 2 * (jn + kk) + 12);
      nm0 = pb0[(jn + kk) >> 3];
      nm1 = pb1[(jn + kk) >> 3];
    }
    const float E1v[8] = {q0.x, q0.z, q1.x, q1.z, q2.x, q2.z, q3.x, q3.z};
    const float E2v[8] = {q0.y, q0.w, q1.y, q1.w, q2.y, q2.w, q3.y, q3.w};
    int p0i[4], p1i[4];
    #pragma unroll
    for (int p = 0; p < 4; ++p) {
      const int e0 = 2 * p, e1 = 2 * p + 1;
      float va0 = fmaxf(c1a * E1v[e0], c2a * E2v[e0]);
      va0 = ((mk0 >> e0) & 1u) ? va0 : 0.f;
      float va1 = fmaxf(c1a * E1v[e1], c2a * E2v[e1]);
      va1 = ((mk0 >> e1) & 1u) ? va1 : 0.f;
      p0i[p] = (int)pk_trunc(va0, va1);
      float vb0 = fmaxf(c1b * E1v[e0], c2b * E2v[e0]);
      vb0 = ((mk1 >> e0) & 1u) ? vb0 : 0.f;
      float vb1 = fmaxf(c1b * E1v[e1], c2b * E2v[e1]);
      vb1 = ((mk1 >> e1) & 1u) ? vb1 : 0.f;
      p1i[p] = (int)pk_trunc(vb0, vb1);
    }
    const short8 p0 = __builtin_bit_cast(short8, (int4v){p0i[0], p0i[1], p0i[2], p0i[3]});
    const short8 p1 = __builtin_bit_cast(short8, (int4v){p1i[0], p1i[1], p1i[2], p1i[3]});
    acc[0][0] = __builtin_amdgcn_mfma_f32_16x16x32_bf16(p0, b0, acc[0][0], 0, 0, 0);
    acc[0][1] = __builtin_amdgcn_mfma_f32_16x16x32_bf16(p0, b1, acc[0][1], 0, 0, 0);
    acc[0][2] = __builtin_amdgcn_mfma_f32_16x16x32_bf16(p0, b2, acc[0][2], 0, 0, 0);
    acc[0][3] = __builtin_amdgcn_mfma_f32_16x16x32_bf16(p0, b3, acc[0][3], 0, 0, 0);
    accL[0]   = __builtin_amdgcn_mfma_f32_16x16x32_bf16(p0, ones, accL[0], 0, 0, 0);
    acc[1][0] = __builtin_amdgcn_mfma_f32_16x16x32_bf16(p1, b0, acc[1][0], 0, 0, 0);
    acc[1][1] = __builtin_amdgcn_mfma_f32_16x16x32_bf16(p1, b1, acc[1][1], 0, 0, 0);
    acc[1][2] = __builtin_amdgcn_mfma_f32_16x16x32_bf16(p1, b2, acc[1][2], 0, 0, 0);
    acc[1][3] = __builtin_amdgcn_mfma_f32_16x16x32_bf16(p1, b3, acc[1][3], 0, 0, 0);
    accL[1]   = __builtin_amdgcn_mfma_f32_16x16x32_bf16(p1, ones, accL[1], 0, 0, 0);
  }

  // ---- combine the 4 j-quarters: q3 -> q2 -> q1 -> q0 ----
  __shared__ float4v parts[4][64][11];   // 44 KiB
  for (int r = 3; r >= 1; --r) {
    if (q == r) {
      #pragma unroll
      for (int rt = 0; rt < 2; ++rt) {
        #pragma unroll
        for (int t = 0; t < 4; ++t) parts[h][lane][rt * 5 + t] = acc[rt][t];
        parts[h][lane][rt * 5 + 4] = accL[rt];
      }
    }
    __syncthreads();
    if (q == r - 1) {
      #pragma unroll
      for (int rt = 0; rt < 2; ++rt) {
        #pragma unroll
        for (int t = 0; t < 4; ++t) acc[rt][t] += parts[h][lane][rt * 5 + t];
        accL[rt] += parts[h][lane][rt * 5 + 4];
      }
    }
    __syncthreads();
  }

  if (q == 0) {
    const int quad = lane >> 4;
    #pragma unroll
    for (int rt = 0; rt < 2; ++rt) {
      #pragma unroll
      for (int reg = 0; reg < 4; ++reg) {
        const int r = i0 + rt * 16 + quad * 4 + reg;
        const float invl = 1.f / accL[rt][reg];
        float* op = out + ((size_t)(b * N) + r) * HF + h * FO + fl;
        #pragma unroll
        for (int t = 0; t < 4; ++t) op[t * 16] = acc[rt][t][reg] * invl;
      }
    }
  }
}

extern "C" void kernel_launch(void* const* d_in, const int* in_sizes, int n_in,
                              void* d_out, int out_size, void* d_ws, size_t ws_size,
                              hipStream_t stream) {
  const float* x     = (const float*)d_in[0];
  const float* adj   = (const float*)d_in[1];
  const float* W     = (const float*)d_in[2];
  const float* a_src = (const float*)d_in[3];
  const float* a_dst = (const float*)d_in[4];
  float* out = (float*)d_out;

  char* p = (char*)d_ws;
  float* Srcv = (float*)p;                 p += (size_t)B * H * N * 4;   // 128 KiB
  float2* Epair = (float2*)p;              p += (size_t)B * H * N * 8;   // 256 KiB
  unsigned int* DmaxEnc = (unsigned int*)p; p += 256;
  unsigned short* Wfh = (unsigned short*)p; p += (size_t)HF * FIN * 2;   // 128 KiB
  unsigned short* Wfl = (unsigned short*)p; p += (size_t)HF * FIN * 2;   // 128 KiB
  unsigned short* Xfh = (unsigned short*)p; p += (size_t)M * FIN * 2;    // 4 MiB
  unsigned short* Xfl = (unsigned short*)p; p += (size_t)M * FIN * 2;    // 4 MiB
  unsigned short* Hf  = (unsigned short*)p; p += (size_t)M * HF * 2;     // 4 MiB
  unsigned long long* packed = (unsigned long long*)p;                   // 512 KiB

  prep_pack<<<dim3(144 + N), dim3(256), 0, stream>>>(W, x, adj, Wfh, Wfl, Xfh, Xfl,
                                                     packed, DmaxEnc);
  gemm_fused<<<dim3((M / 64) * H), dim3(256), 0, stream>>>(Xfh, Xfl, Wfh, Wfl,
                                                           a_src, a_dst,
                                                           Srcv, Epair, DmaxEnc, Hf);
  gat_mfma<<<dim3(B * (N / 32)), dim3(1024), 0, stream>>>((const unsigned char*)packed,
                                                          Srcv, Epair, DmaxEnc, Hf, out);
}

// Round 14
// 126.677 us; speedup vs baseline: 1.0533x; 1.0533x over previous
//
#include <hip/hip_runtime.h>
#include <hip/hip_bf16.h>
#include <math.h>

#define B 4
#define N 2048
#define FIN 256
#define H 4
#define FO 64
#define M (B*N)        // 8192 rows
#define HF (H*FO)      // 256 cols

typedef __attribute__((ext_vector_type(8))) short short8;   // 8 bf16 (4 VGPRs)
typedef __attribute__((ext_vector_type(4))) float float4v;  // MFMA C/D
typedef __attribute__((ext_vector_type(4))) int int4v;

#if __has_builtin(__builtin_amdgcn_exp2f)
#define EXP2(x) __builtin_amdgcn_exp2f(x)
#else
#define EXP2(x) exp2f(x)
#endif

// pack two f32 -> two bf16 (RNE) in one dword
static __device__ __forceinline__ unsigned int pk_rne(float a, float b) {
  unsigned int ua = __builtin_bit_cast(unsigned int, a);
  unsigned int ub = __builtin_bit_cast(unsigned int, b);
  ua += 0x7fffu + ((ua >> 16) & 1u);
  ub += 0x7fffu + ((ub >> 16) & 1u);
  return (ua >> 16) | (ub & 0xffff0000u);
}

// pack two f32 -> two bf16 (truncate) in one dword: 1 v_perm_b32
static __device__ __forceinline__ unsigned int pk_trunc(float a, float b) {
#if __has_builtin(__builtin_amdgcn_perm)
  return __builtin_amdgcn_perm(__builtin_bit_cast(unsigned int, b),
                               __builtin_bit_cast(unsigned int, a), 0x07060302u);
#else
  return (__builtin_bit_cast(unsigned int, a) >> 16) |
         (__builtin_bit_cast(unsigned int, b) & 0xffff0000u);
#endif
}

// split x into hi (truncated bf16) + lo (truncated bf16 of remainder), packed pairs
static __device__ __forceinline__ void split_pair(float x0, float x1,
                                                  unsigned int& hi, unsigned int& lo) {
  unsigned int u0 = __builtin_bit_cast(unsigned int, x0);
  unsigned int u1 = __builtin_bit_cast(unsigned int, x1);
  hi = (u0 >> 16) | (u1 & 0xffff0000u);
  float h0 = __builtin_bit_cast(float, u0 & 0xffff0000u);
  float h1 = __builtin_bit_cast(float, u1 & 0xffff0000u);
  unsigned int l0 = __builtin_bit_cast(unsigned int, x0 - h0);
  unsigned int l1 = __builtin_bit_cast(unsigned int, x1 - h1);
  lo = (l0 >> 16) | (l1 & 0xffff0000u);
}

// monotone float<->uint encoding for atomicMax
static __device__ __forceinline__ unsigned int fenc(float f) {
  unsigned int b = __builtin_bit_cast(unsigned int, f);
  return (b & 0x80000000u) ? ~b : (b | 0x80000000u);
}
static __device__ __forceinline__ float fdec(unsigned int e) {
  unsigned int b = (e & 0x80000000u) ? (e & 0x7fffffffu) : ~e;
  return __builtin_bit_cast(float, b);
}

// ---- Kernel 1: [0..15] W -> Wf (fragment-ordered bf16 hi/lo pair)
//      [16..143] X -> Xf (fragment-ordered A-operand bf16 hi/lo pair)
// (adj packing moved into the gemm_fused dispatch for overlap — r14)
__global__ __launch_bounds__(256) void prep_wx(const float* __restrict__ Wsrc,
                                               const float* __restrict__ X,
                                               unsigned short* __restrict__ Wf_hi,
                                               unsigned short* __restrict__ Wf_lo,
                                               unsigned short* __restrict__ Xf_hi,
                                               unsigned short* __restrict__ Xf_lo,
                                               unsigned int* __restrict__ DmaxEnc) {
  const int blk = blockIdx.x;
  const int t = threadIdx.x;
  __shared__ float lds[64][65];
  if (blk < 16) {
    if (blk == 0 && t < 16) DmaxEnc[t] = 0u;
    const int k0 = (blk >> 2) * 64;
    const int h  = blk & 3;
    const int n0 = h * 64;
    const int c4 = (t & 15) * 4;
    #pragma unroll
    for (int rep = 0; rep < 4; ++rep) {
      const int kl = (t >> 4) + 16 * rep;
      const float4 v = *(const float4*)(Wsrc + (size_t)(k0 + kl) * HF + n0 + c4);
      lds[kl][c4 + 0] = v.x; lds[kl][c4 + 1] = v.y;
      lds[kl][c4 + 2] = v.z; lds[kl][c4 + 3] = v.w;
    }
    __syncthreads();
    #pragma unroll
    for (int rep = 0; rep < 2; ++rep) {
      const int s   = t + rep * 256;
      const int kcl = s >> 8;
      const int tt  = (s >> 6) & 3;
      const int ln  = s & 63;
      const int fL  = tt * 16 + (ln & 15);
      const int kb  = kcl * 32 + (ln >> 4) * 8;
      unsigned int hv[4], lv[4];
      #pragma unroll
      for (int p = 0; p < 4; ++p)
        split_pair(lds[kb + 2 * p][fL], lds[kb + 2 * p + 1][fL], hv[p], lv[p]);
      const size_t off = ((((size_t)h * 8 + (k0 >> 5) + kcl) * 4 + tt) << 9) + ln * 8;
      *(uint4*)(Wf_hi + off) = make_uint4(hv[0], hv[1], hv[2], hv[3]);
      *(uint4*)(Wf_lo + off) = make_uint4(lv[0], lv[1], lv[2], lv[3]);
    }
    return;
  }
  // ---- X prep: xblk in [0,128), rows xblk*64..+64, A-fragment order ----
  const int xblk  = blk - 16;
  const int mrow0 = xblk * 64;
  for (int ktile = 0; ktile < 4; ++ktile) {
    if (ktile) __syncthreads();
    const int k0 = ktile * 64;
    const int c4 = (t & 15) * 4;
    #pragma unroll
    for (int rep = 0; rep < 4; ++rep) {
      const int rl = (t >> 4) + 16 * rep;
      const float4 v = *(const float4*)(X + (size_t)(mrow0 + rl) * FIN + k0 + c4);
      lds[rl][c4 + 0] = v.x; lds[rl][c4 + 1] = v.y;
      lds[rl][c4 + 2] = v.z; lds[rl][c4 + 3] = v.w;
    }
    __syncthreads();
    #pragma unroll
    for (int rep = 0; rep < 2; ++rep) {
      const int s   = t + rep * 256;
      const int mt  = s >> 7;
      const int kcl = (s >> 6) & 1;
      const int ln  = s & 63;
      const int mrl = mt * 16 + (ln & 15);
      const int kb  = kcl * 32 + (ln >> 4) * 8;
      unsigned int hv[4], lv[4];
      #pragma unroll
      for (int p = 0; p < 4; ++p)
        split_pair(lds[mrl][kb + 2 * p], lds[mrl][kb + 2 * p + 1], hv[p], lv[p]);
      const size_t off = (((size_t)(xblk * 4 + mt) * 8 + (ktile * 2 + kcl)) << 9) + ln * 8;
      *(uint4*)(Xf_hi + off) = make_uint4(hv[0], hv[1], hv[2], hv[3]);
      *(uint4*)(Xf_lo + off) = make_uint4(lv[0], lv[1], lv[2], lv[3]);
    }
  }
}

// ---- Kernel 2: [0..511] fused h=x@W (bf16x2 MFMA) + epilogue
//      [512..2559] adj rows -> bitmasks (overlaps with gemm blocks)
__global__ __launch_bounds__(256) void gemm_fused(const unsigned short* __restrict__ Xf_hi,
                                                  const unsigned short* __restrict__ Xf_lo,
                                                  const unsigned short* __restrict__ Wf_hi,
                                                  const unsigned short* __restrict__ Wf_lo,
                                                  const float* __restrict__ adj,
                                                  const float* __restrict__ a_src,
                                                  const float* __restrict__ a_dst,
                                                  float* __restrict__ Srcv,
                                                  float2* __restrict__ Epair,
                                                  unsigned int* __restrict__ DmaxEnc,
                                                  unsigned long long* __restrict__ packed,
                                                  unsigned short* __restrict__ Hf) {
  if (blockIdx.x >= 512) {
    const int row = blockIdx.x - 512;
    const int pw = threadIdx.x >> 6, pl = threadIdx.x & 63;
    const float* ar = adj + (size_t)row * N;
    for (int c = pw; c < N / 64; c += 4) {
      unsigned long long m = __ballot(ar[c * 64 + pl] != 0.f);
      if (pl == 0) packed[(size_t)row * (N / 64) + c] = m;
    }
    return;
  }
  __shared__ unsigned short sh[64][72];
  __shared__ float smax[4];
  const int xcd  = blockIdx.x & 7;
  const int slot = blockIdx.x >> 3;
  const int mb = xcd * 16 + (slot >> 2);
  const int h  = slot & 3;
  const int w = threadIdx.x >> 6, lane = threadIdx.x & 63;
  const int fl = lane & 15, quad = lane >> 4;
  const float L2E = 1.4426950408889634f;

  const float4v zero = {0.f, 0.f, 0.f, 0.f};
  float4v acc[4] = {zero, zero, zero, zero};

  const size_t abase = (((size_t)(mb * 4 + w) * 8) << 9) + lane * 8;
  #pragma unroll
  for (int kc = 0; kc < 8; ++kc) {
    const short8 Ahi = *(const short8*)(Xf_hi + abase + ((size_t)kc << 9));
    const short8 Alo = *(const short8*)(Xf_lo + abase + ((size_t)kc << 9));
    #pragma unroll
    for (int t = 0; t < 4; ++t) {
      const size_t woff = ((((size_t)h * 8 + kc) * 4 + t) << 9) + lane * 8;
      const short8 Bhi = *(const short8*)(Wf_hi + woff);
      const short8 Blo = *(const short8*)(Wf_lo + woff);
      acc[t] = __builtin_amdgcn_mfma_f32_16x16x32_bf16(Ahi, Bhi, acc[t], 0, 0, 0);
      acc[t] = __builtin_amdgcn_mfma_f32_16x16x32_bf16(Alo, Bhi, acc[t], 0, 0, 0);
      acc[t] = __builtin_amdgcn_mfma_f32_16x16x32_bf16(Ahi, Blo, acc[t], 0, 0, 0);
    }
  }

  // ---- Src dot, E-pair, wave max of d ----
  const int bb  = (mb * 64) >> 11;
  const int n0w = (mb * 64) & (N - 1);
  const int bh  = bb * H + h;
  float as[4], ad[4];
  #pragma unroll
  for (int t = 0; t < 4; ++t) {
    as[t] = a_src[h * FO + t * 16 + fl];
    ad[t] = a_dst[h * FO + t * 16 + fl];
  }
  float wmax = -INFINITY;
  #pragma unroll
  for (int reg = 0; reg < 4; ++reg) {
    float sv = 0.f, dv = 0.f;
    #pragma unroll
    for (int t = 0; t < 4; ++t) {
      sv = fmaf(acc[t][reg], as[t], sv);
      dv = fmaf(acc[t][reg], ad[t], dv);
    }
    #pragma unroll
    for (int off = 1; off <= 8; off <<= 1) {
      sv += __shfl_xor(sv, off, 64);
      dv += __shfl_xor(dv, off, 64);
    }
    wmax = fmaxf(wmax, dv);
    if (fl == 0) {
      const int node = n0w + w * 16 + quad * 4 + reg;
      Srcv[(bh << 11) + node] = sv;
      float2 e;
      e.x = EXP2(dv * L2E);            // exp(d)
      e.y = EXP2(dv * (0.2f * L2E));   // exp(0.2 d)
      Epair[(bh << 11) + node] = e;
    }
  }
  wmax = fmaxf(wmax, __shfl_xor(wmax, 16, 64));
  wmax = fmaxf(wmax, __shfl_xor(wmax, 32, 64));
  if (lane == 0) smax[w] = wmax;

  // ---- stage bf16 tile: sh[f][node] ----
  #pragma unroll
  for (int t = 0; t < 4; ++t) {
    const int nl = w * 16 + quad * 4;
    *(unsigned int*)&sh[t * 16 + fl][nl]     = pk_rne(acc[t][0], acc[t][1]);
    *(unsigned int*)&sh[t * 16 + fl][nl + 2] = pk_rne(acc[t][2], acc[t][3]);
  }
  __syncthreads();
  if (threadIdx.x == 0) {
    const float bmax = fmaxf(fmaxf(smax[0], smax[1]), fmaxf(smax[2], smax[3]));
    atomicMax(DmaxEnc + bh, fenc(bmax));
  }
  // ---- fragment-ordered Hf write ----
  const int jc0 = n0w >> 5;
  #pragma unroll
  for (int rep = 0; rep < 2; ++rep) {
    const int s = (int)threadIdx.x + rep * 256;
    const int jcl = s >> 8;
    const int tt  = (s >> 6) & 3;
    const int ln  = s & 63;
    const int f    = tt * 16 + (ln & 15);
    const int node = jcl * 32 + (ln >> 4) * 8;
    unsigned short* dsth = Hf + (((size_t)bh * 64 + jc0 + jcl) * 4 + tt) * 512 + ln * 8;
    *(uint4*)dsth = *(const uint4*)&sh[f][node];
  }
}

// ---- Kernel 3: MFMA flash aggregation (r12 version verbatim — best measured)
// Grid: B*(N/32)=256 blocks, 512 thr (8 waves: 4 heads x 2 j-halves).
// Register double-buffer covers L2 latency with chunk compute.
// NOTE: plain __launch_bounds__ — min-waves bound splits unified VGPR/AGPR
// file and spills (r9: 172MB scratch traffic). Never force it.
__global__ __launch_bounds__(512) void gat_mfma(const unsigned char* __restrict__ pb,
                                                const float* __restrict__ Src,
                                                const float2* __restrict__ Epair,
                                                const unsigned int* __restrict__ DmaxEnc,
                                                const unsigned short* __restrict__ Hf,
                                                float* __restrict__ out) {
  const int xcd  = blockIdx.x & 7;
  const int slot = blockIdx.x >> 3;          // 0..31
  const int b    = xcd >> 1;
  const int i0   = ((xcd & 1) * 32 + slot) * 32;
  const int w    = threadIdx.x >> 6;         // 0..7
  const int lane = threadIdx.x & 63;
  const int h    = w & 3;
  const int jh   = w >> 2;                   // j half
  const int bh   = b * H + h;
  const int fl   = lane & 15;
  const int kk   = (lane >> 4) * 8;
  const float L2E = 1.4426950408889634f;

  const int row0 = i0 + fl;
  const int row1 = i0 + 16 + fl;
  const float dmx = fdec(DmaxEnc[bh]);
  const float s0 = Src[(bh << 11) + row0];
  const float s1 = Src[(bh << 11) + row1];
  const float u0 = s0 + dmx, m0 = fmaxf(u0, 0.2f * u0);
  const float u1 = s1 + dmx, m1 = fmaxf(u1, 0.2f * u1);
  const float c1a = EXP2((s0 - m0) * L2E), c2a = EXP2((0.2f * s0 - m0) * L2E);
  const float c1b = EXP2((s1 - m1) * L2E), c2b = EXP2((0.2f * s1 - m1) * L2E);
  const float ta = EXP2(-s0 * L2E), tb = EXP2(-s1 * L2E);
  const float* ep = (const float*)(Epair + (bh << 11));
  const unsigned char* pb0 = pb + (size_t)row0 * (N / 8);
  const unsigned char* pb1 = pb + (size_t)row1 * (N / 8);
  const unsigned short* hfb = Hf + (size_t)bh * 64 * 2048 + lane * 8;

  const short onebf = 0x3F80;
  short8 ones;
  #pragma unroll
  for (int jj = 0; jj < 8; ++jj) ones[jj] = onebf;

  const float4v zero = {0.f, 0.f, 0.f, 0.f};
  float4v acc[2][4];
  float4v accL[2];
  #pragma unroll
  for (int rt = 0; rt < 2; ++rt) {
    accL[rt] = zero;
    #pragma unroll
    for (int t = 0; t < 4; ++t) acc[rt][t] = zero;
  }

  const int jbeg = jh * (N / 2);
  // ---- prefetch chunk 0 ----
  short8 nb0, nb1, nb2, nb3;
  float4 nq0, nq1, nq2, nq3;
  unsigned int nm0, nm1;
  {
    const unsigned short* hc = hfb + (size_t)(jbeg >> 5) * 2048;
    nb0 = *(const short8*)(hc + 0 * 512);
    nb1 = *(const short8*)(hc + 1 * 512);
    nb2 = *(const short8*)(hc + 2 * 512);
    nb3 = *(const short8*)(hc + 3 * 512);
    nq0 = *(const float4*)(ep + 2 * (jbeg + kk) + 0);
    nq1 = *(const float4*)(ep + 2 * (jbeg + kk) + 4);
    nq2 = *(const float4*)(ep + 2 * (jbeg + kk) + 8);
    nq3 = *(const float4*)(ep + 2 * (jbeg + kk) + 12);
    nm0 = pb0[(jbeg + kk) >> 3];
    nm1 = pb1[(jbeg + kk) >> 3];
  }

  for (int it = 0; it < 32; ++it) {
    const short8 b0 = nb0, b1 = nb1, b2 = nb2, b3 = nb3;
    const float4 q0 = nq0, q1 = nq1, q2 = nq2, q3 = nq3;
    const unsigned int mk0 = nm0, mk1 = nm1;
    if (it < 31) {
      const int jn = jbeg + (it + 1) * 32;
      const unsigned short* hc = hfb + (size_t)(jn >> 5) * 2048;
      nb0 = *(const short8*)(hc + 0 * 512);
      nb1 = *(const short8*)(hc + 1 * 512);
      nb2 = *(const short8*)(hc + 2 * 512);
      nb3 = *(const short8*)(hc + 3 * 512);
      nq0 = *(const float4*)(ep + 2 * (jn + kk) + 0);
      nq1 = *(const float4*)(ep + 2 * (jn + kk) + 4);
      nq2 = *(const float4*)(ep + 2 * (jn + kk) + 8);
      nq3 = *(const float4*)(ep + 2 * (jn + kk) + 12);
      nm0 = pb0[(jn + kk) >> 3];
      nm1 = pb1[(jn + kk) >> 3];
    }
    const float E1v[8] = {q0.x, q0.z, q1.x, q1.z, q2.x, q2.z, q3.x, q3.z};
    const float E2v[8] = {q0.y, q0.w, q1.y, q1.w, q2.y, q2.w, q3.y, q3.w};
    int p0i[4], p1i[4];
    #pragma unroll
    for (int p = 0; p < 4; ++p) {
      const int e0 = 2 * p, e1 = 2 * p + 1;
      const bool sa0 = E1v[e0] > ta;
      float va0 = (sa0 ? c1a : c2a) * (sa0 ? E1v[e0] : E2v[e0]);
      va0 = ((mk0 >> e0) & 1u) ? va0 : 0.f;
      const bool sa1 = E1v[e1] > ta;
      float va1 = (sa1 ? c1a : c2a) * (sa1 ? E1v[e1] : E2v[e1]);
      va1 = ((mk0 >> e1) & 1u) ? va1 : 0.f;
      p0i[p] = (int)pk_trunc(va0, va1);
      const bool sb0 = E1v[e0] > tb;
      float vb0 = (sb0 ? c1b : c2b) * (sb0 ? E1v[e0] : E2v[e0]);
      vb0 = ((mk1 >> e0) & 1u) ? vb0 : 0.f;
      const bool sb1 = E1v[e1] > tb;
      float vb1 = (sb1 ? c1b : c2b) * (sb1 ? E1v[e1] : E2v[e1]);
      vb1 = ((mk1 >> e1) & 1u) ? vb1 : 0.f;
      p1i[p] = (int)pk_trunc(vb0, vb1);
    }
    const short8 p0 = __builtin_bit_cast(short8, (int4v){p0i[0], p0i[1], p0i[2], p0i[3]});
    const short8 p1 = __builtin_bit_cast(short8, (int4v){p1i[0], p1i[1], p1i[2], p1i[3]});
    acc[0][0] = __builtin_amdgcn_mfma_f32_16x16x32_bf16(p0, b0, acc[0][0], 0, 0, 0);
    acc[0][1] = __builtin_amdgcn_mfma_f32_16x16x32_bf16(p0, b1, acc[0][1], 0, 0, 0);
    acc[0][2] = __builtin_amdgcn_mfma_f32_16x16x32_bf16(p0, b2, acc[0][2], 0, 0, 0);
    acc[0][3] = __builtin_amdgcn_mfma_f32_16x16x32_bf16(p0, b3, acc[0][3], 0, 0, 0);
    accL[0]   = __builtin_amdgcn_mfma_f32_16x16x32_bf16(p0, ones, accL[0], 0, 0, 0);
    acc[1][0] = __builtin_amdgcn_mfma_f32_16x16x32_bf16(p1, b0, acc[1][0], 0, 0, 0);
    acc[1][1] = __builtin_amdgcn_mfma_f32_16x16x32_bf16(p1, b1, acc[1][1], 0, 0, 0);
    acc[1][2] = __builtin_amdgcn_mfma_f32_16x16x32_bf16(p1, b2, acc[1][2], 0, 0, 0);
    acc[1][3] = __builtin_amdgcn_mfma_f32_16x16x32_bf16(p1, b3, acc[1][3], 0, 0, 0);
    accL[1]   = __builtin_amdgcn_mfma_f32_16x16x32_bf16(p1, ones, accL[1], 0, 0, 0);
  }

  // ---- combine the 2 j-halves: jh1 -> jh0 ----
  __shared__ float4v parts[4][64][11];   // 44 KiB
  if (jh == 1) {
    #pragma unroll
    for (int rt = 0; rt < 2; ++rt) {
      #pragma unroll
      for (int t = 0; t < 4; ++t) parts[h][lane][rt * 5 + t] = acc[rt][t];
      parts[h][lane][rt * 5 + 4] = accL[rt];
    }
  }
  __syncthreads();
  if (jh == 0) {
    #pragma unroll
    for (int rt = 0; rt < 2; ++rt) {
      #pragma unroll
      for (int t = 0; t < 4; ++t) acc[rt][t] += parts[h][lane][rt * 5 + t];
      accL[rt] += parts[h][lane][rt * 5 + 4];
    }
    const int quad = lane >> 4;
    #pragma unroll
    for (int rt = 0; rt < 2; ++rt) {
      #pragma unroll
      for (int reg = 0; reg < 4; ++reg) {
        const int r = i0 + rt * 16 + quad * 4 + reg;
        const float invl = 1.f / accL[rt][reg];
        float* op = out + ((size_t)(b * N) + r) * HF + h * FO + fl;
        #pragma unroll
        for (int t = 0; t < 4; ++t) op[t * 16] = acc[rt][t][reg] * invl;
      }
    }
  }
}

extern "C" void kernel_launch(void* const* d_in, const int* in_sizes, int n_in,
                              void* d_out, int out_size, void* d_ws, size_t ws_size,
                              hipStream_t stream) {
  const float* x     = (const float*)d_in[0];
  const float* adj   = (const float*)d_in[1];
  const float* W     = (const float*)d_in[2];
  const float* a_src = (const float*)d_in[3];
  const float* a_dst = (const float*)d_in[4];
  float* out = (float*)d_out;

  char* p = (char*)d_ws;
  float* Srcv = (float*)p;                 p += (size_t)B * H * N * 4;   // 128 KiB
  float2* Epair = (float2*)p;              p += (size_t)B * H * N * 8;   // 256 KiB
  unsigned int* DmaxEnc = (unsigned int*)p; p += 256;
  unsigned short* Wfh = (unsigned short*)p; p += (size_t)HF * FIN * 2;   // 128 KiB
  unsigned short* Wfl = (unsigned short*)p; p += (size_t)HF * FIN * 2;   // 128 KiB
  unsigned short* Xfh = (unsigned short*)p; p += (size_t)M * FIN * 2;    // 4 MiB
  unsigned short* Xfl = (unsigned short*)p; p += (size_t)M * FIN * 2;    // 4 MiB
  unsigned short* Hf  = (unsigned short*)p; p += (size_t)M * HF * 2;     // 4 MiB
  unsigned long long* packed = (unsigned long long*)p;                   // 512 KiB

  prep_wx<<<dim3(144), dim3(256), 0, stream>>>(W, x, Wfh, Wfl, Xfh, Xfl, DmaxEnc);
  gemm_fused<<<dim3(512 + N), dim3(256), 0, stream>>>(Xfh, Xfl, Wfh, Wfl, adj,
                                                      a_src, a_dst,
                                                      Srcv, Epair, DmaxEnc,
                                                      packed, Hf);
  gat_mfma<<<dim3(B * (N / 32)), dim3(512), 0, stream>>>((const unsigned char*)packed,
                                                         Srcv, Epair, DmaxEnc, Hf, out);
}